// Round 6
// baseline (150.585 us; speedup 1.0000x reference)
//
#include <hip/hip_runtime.h>

#define NN 50000
#define NE 500000
#define DD 128
#define NCHUNK ((NN + 15) / 16)

typedef __attribute__((ext_vector_type(8))) short bf16x8;
typedef __attribute__((ext_vector_type(4))) float f32x4;

// ---------------------------------------------------------------------------
// Math: xs[n] = bf16( (x@W)[n] * dinv[n] )          (12.8 MB gather table)
//       out[d] = relu( dinv[d] * (xs[d] + sum_{e: dst=d} xs[src_e]) + b )
// CSR built by counting sort on dst. deg[d] = hist[d] + 1 (self-loop).
// GEMM via mfma_f32_16x16x32_bf16. Aggregation is XCD-sliced: feature dims
// split into 4 slices of 32; each slice pinned to one XCD pair so the
// 3.2 MB slice table lives in that pair's L2.
// ---------------------------------------------------------------------------

__device__ __forceinline__ unsigned int bf16pair(float a, float b) {
    unsigned int ua = __float_as_uint(a);
    ua = (ua + 0x7FFFu + ((ua >> 16) & 1u)) >> 16;   // RNE
    unsigned int ub = __float_as_uint(b);
    ub = (ub + 0x7FFFu + ((ub >> 16) & 1u)) >> 16;
    return ua | (ub << 16);
}

__global__ void k_zero(int* __restrict__ p, int n) {
    int i = blockIdx.x * blockDim.x + threadIdx.x;
    if (i < n) p[i] = 0;
}

// Normalize edge_index (int32 or int64) into int32 src/dst + dst histogram.
__global__ void k_convert_hist(const int* __restrict__ ei, int* __restrict__ src,
                               int* __restrict__ dst, int* __restrict__ cnt, int e) {
    int i = blockIdx.x * blockDim.x + threadIdx.x;
    if (i >= e) return;
    bool is64 = (ei[1] == 0) & (ei[3] == 0) & (ei[5] == 0) & (ei[7] == 0);
    int s, d;
    if (is64) {
        s = ei[2 * i];
        d = ei[2 * (e + i)];
    } else {
        s = ei[i];
        d = ei[e + i];
    }
    src[i] = s;
    dst[i] = d;
    atomicAdd(&cnt[d], 1);
}

// exclusive scan of cnt (1024/block) + dinv = rsqrt(cnt+1)
__global__ void k_scan1(const int* __restrict__ cnt, int* __restrict__ rowptr,
                        int* __restrict__ bsum, float* __restrict__ dinv, int n) {
    __shared__ int ts[256];
    int t = threadIdx.x;
    int base = blockIdx.x * 1024 + t * 4;
    int v[4];
    int s = 0;
#pragma unroll
    for (int i = 0; i < 4; ++i) {
        int idx = base + i;
        v[i] = (idx < n) ? cnt[idx] : 0;
        if (idx < n) dinv[idx] = rsqrtf((float)v[i] + 1.0f);
        s += v[i];
    }
    ts[t] = s;
    __syncthreads();
    for (int off = 1; off < 256; off <<= 1) {
        int x = (t >= off) ? ts[t - off] : 0;
        __syncthreads();
        ts[t] += x;
        __syncthreads();
    }
    if (t == 255) bsum[blockIdx.x] = ts[255];
    int run = ts[t] - s;
#pragma unroll
    for (int i = 0; i < 4; ++i) {
        int idx = base + i;
        if (idx < n) rowptr[idx] = run;
        run += v[i];
    }
}

__global__ void k_scan2(int* __restrict__ bsum, int nb) {
    __shared__ int ts[64];
    int t = threadIdx.x;
    int v = (t < nb) ? bsum[t] : 0;
    ts[t] = v;
    __syncthreads();
    for (int off = 1; off < 64; off <<= 1) {
        int x = (t >= off) ? ts[t - off] : 0;
        __syncthreads();
        ts[t] += x;
        __syncthreads();
    }
    if (t < nb) bsum[t] = ts[t] - v;
}

__global__ void k_scan3(int* __restrict__ rowptr, const int* __restrict__ bsum,
                        int* __restrict__ cursor, int n, int e) {
    int i = blockIdx.x * blockDim.x + threadIdx.x;
    if (i < n) {
        int r = rowptr[i] + bsum[i >> 10];
        rowptr[i] = r;
        cursor[i] = r;
    }
    if (i == n) rowptr[n] = e;
}

__global__ void k_esort(const int* __restrict__ src, const int* __restrict__ dst,
                        int* __restrict__ cursor, int* __restrict__ col, int e) {
    int i = blockIdx.x * blockDim.x + threadIdx.x;
    if (i >= e) return;
    int pos = atomicAdd(&cursor[dst[i]], 1);
    col[pos] = src[i];
}

// Repack W into B-fragment-linear bf16 (see R4).
__global__ void k_wfrag(const float* __restrict__ W, unsigned int* __restrict__ Wf) {
    int id = blockIdx.x * blockDim.x + threadIdx.x;  // 0..2047
    if (id >= 2048) return;
    int lane = id & 63;
    int ts = id >> 6;
    int t8 = ts >> 2, s = ts & 3;
    int col = t8 * 16 + (lane & 15);
    int k0 = s * 32 + (lane >> 4) * 8;
    unsigned int w[4];
#pragma unroll
    for (int j = 0; j < 4; ++j) {
        float a = W[(k0 + 2 * j) * DD + col];
        float bb = W[(k0 + 2 * j + 1) * DD + col];
        w[j] = bf16pair(a, bb);
    }
    Wf[id * 4 + 0] = w[0];
    Wf[id * 4 + 1] = w[1];
    Wf[id * 4 + 2] = w[2];
    Wf[id * 4 + 3] = w[3];
}

// xs = bf16( (x @ W) * dinv[row] ) via MFMA. 4 waves/block, 16 rows/wave.
__global__ __launch_bounds__(256) void k_gemm(
    const float* __restrict__ x, const unsigned int* __restrict__ Wf,
    const float* __restrict__ dinv, unsigned short* __restrict__ xs, int n) {
    const int t = threadIdx.x;
    const int wave = t >> 6, lane = t & 63;
    const int row0 = blockIdx.x * 64 + wave * 16;
    const int arow = min(row0 + (lane & 15), n - 1);  // clamp; stores guarded
    const int kbase = (lane >> 4) * 8;

    bf16x8 af[4];
#pragma unroll
    for (int s = 0; s < 4; ++s) {
        const float* px = &x[(size_t)arow * DD + s * 32 + kbase];
        float4 a0 = *(const float4*)px;
        float4 a1 = *(const float4*)(px + 4);
        unsigned int p[4];
        p[0] = bf16pair(a0.x, a0.y);
        p[1] = bf16pair(a0.z, a0.w);
        p[2] = bf16pair(a1.x, a1.y);
        p[3] = bf16pair(a1.z, a1.w);
        af[s] = __builtin_bit_cast(bf16x8, *(f32x4*)p);
    }

    f32x4 acc[8] = {};
#pragma unroll
    for (int s = 0; s < 4; ++s) {
#pragma unroll
        for (int t8 = 0; t8 < 8; ++t8) {
            bf16x8 bf = *(const bf16x8*)&Wf[((t8 * 4 + s) * 64 + lane) * 4];
            acc[t8] = __builtin_amdgcn_mfma_f32_16x16x32_bf16(af[s], bf, acc[t8], 0, 0, 0);
        }
    }

    const int rrow0 = row0 + (lane >> 4) * 4;
    const int colb = lane & 15;
#pragma unroll
    for (int i = 0; i < 4; ++i) {
        int r = rrow0 + i;
        if (r < n) {
            float dv = dinv[r];
#pragma unroll
            for (int t8 = 0; t8 < 8; ++t8) {
                float v = acc[t8][i] * dv;
                unsigned int uv = __float_as_uint(v);
                uv = (uv + 0x7FFFu + ((uv >> 16) & 1u)) >> 16;
                xs[(size_t)r * DD + t8 * 16 + colb] = (unsigned short)uv;
            }
        }
    }
}

// XCD-sliced aggregation.
// slice = 32 dims = 16 dwords; 4 slices. Block -> (slice, chunk of 16 dst):
//   slice = (blk&7)>>1  (XCD pair via round-robin dispatch), chunk = (blk>>3)*2 + (blk&1).
// Wave = 4 dst groups x 16 lanes; lane q owns dwords (dims 2q,2q+1) of the slice.
__global__ __launch_bounds__(256) void k_aggr(
    const int* __restrict__ rowptr, const int* __restrict__ col,
    const unsigned int* __restrict__ xs, const float* __restrict__ dinv,
    const float* __restrict__ b, float* __restrict__ out) {
    const int blk = blockIdx.x;
    const int slice = (blk & 7) >> 1;
    const int chunk = (blk >> 3) * 2 + (blk & 1);
    if (chunk >= NCHUNK) return;
    const int t = threadIdx.x;
    const int wave = t >> 6, lane = t & 63;
    const int g = lane >> 4, q = lane & 15;
    const int dst = chunk * 16 + wave * 4 + g;
    if (dst >= NN) return;
    const int soff = slice * 16;

    int beg = rowptr[dst], end = rowptr[dst + 1];
    unsigned int u = xs[(size_t)dst * 64 + soff + q];   // self-loop term
    float ax = __uint_as_float(u << 16);
    float ay = __uint_as_float(u & 0xFFFF0000u);
    int j = beg;
    for (; j + 2 <= end; j += 2) {
        int s0 = __builtin_nontemporal_load(col + j);
        int s1 = __builtin_nontemporal_load(col + j + 1);
        unsigned int u0 = xs[(size_t)s0 * 64 + soff + q];
        unsigned int u1 = xs[(size_t)s1 * 64 + soff + q];
        ax += __uint_as_float(u0 << 16) + __uint_as_float(u1 << 16);
        ay += __uint_as_float(u0 & 0xFFFF0000u) + __uint_as_float(u1 & 0xFFFF0000u);
    }
    if (j < end) {
        int s0 = __builtin_nontemporal_load(col + j);
        unsigned int u0 = xs[(size_t)s0 * 64 + soff + q];
        ax += __uint_as_float(u0 << 16);
        ay += __uint_as_float(u0 & 0xFFFF0000u);
    }
    float dv = dinv[dst];
    float2 bb = *(const float2*)&b[slice * 32 + q * 2];
    float ox = fmaxf(fmaf(ax, dv, bb.x), 0.f);
    float oy = fmaxf(fmaf(ay, dv, bb.y), 0.f);
    *(float2*)&out[(size_t)dst * DD + slice * 32 + q * 2] = make_float2(ox, oy);
}

extern "C" void kernel_launch(void* const* d_in, const int* in_sizes, int n_in,
                              void* d_out, int out_size, void* d_ws, size_t ws_size,
                              hipStream_t stream) {
    const float* x  = (const float*)d_in[0];
    const int*   ei = (const int*)d_in[1];
    const float* W  = (const float*)d_in[2];
    const float* b  = (const float*)d_in[3];
    float* out = (float*)d_out;

    char* p = (char*)d_ws;
    float*          dinv   = (float*)p;          p += NN * sizeof(float);
    unsigned short* xs     = (unsigned short*)p; p += (size_t)NN * DD * sizeof(unsigned short);
    int*            srcW   = (int*)p;            p += NE * sizeof(int);
    int*            dstW   = (int*)p;            p += NE * sizeof(int);
    int*            colW   = (int*)p;            p += NE * sizeof(int);
    int*            cnt    = (int*)p;            p += NN * sizeof(int);
    int*            rowptr = (int*)p;            p += (NN + 1) * sizeof(int);
    int*            cursor = (int*)p;            p += NN * sizeof(int);
    int*            bsum   = (int*)p;            p += 64 * sizeof(int);
    unsigned int*   Wf     = (unsigned int*)p;   p += 2048 * 4 * sizeof(unsigned int);

    const int nb256_e = (NE + 255) / 256;
    const int nscan   = (NN + 1023) / 1024;  // 49

    k_zero<<<(NN + 255) / 256, 256, 0, stream>>>(cnt, NN);
    k_convert_hist<<<nb256_e, 256, 0, stream>>>(ei, srcW, dstW, cnt, NE);
    k_wfrag<<<8, 256, 0, stream>>>(W, Wf);
    k_scan1<<<nscan, 256, 0, stream>>>(cnt, rowptr, bsum, dinv, NN);
    k_scan2<<<1, 64, 0, stream>>>(bsum, nscan);
    k_scan3<<<(NN + 256) / 256, 256, 0, stream>>>(rowptr, bsum, cursor, NN, NE);
    k_esort<<<nb256_e, 256, 0, stream>>>(srcW, dstW, cursor, colW, NE);
    k_gemm<<<(NN + 63) / 64, 256, 0, stream>>>(x, Wf, dinv, xs, NN);
    // 8 residues x 1563 chunk-pairs covers each (chunk, slice) exactly once
    k_aggr<<<8 * ((NCHUNK + 1) / 2), 256, 0, stream>>>(rowptr, colW,
                                                       (const unsigned int*)xs, dinv, b, out);
}

// Round 7
// 96.119 us; speedup vs baseline: 1.5667x; 1.5667x over previous
//
#include <hip/hip_runtime.h>

#define NN 50000
#define NE 500000
#define DD 128

typedef __attribute__((ext_vector_type(8))) short bf16x8;
typedef __attribute__((ext_vector_type(4))) float f32x4;

// ---------------------------------------------------------------------------
// Math: xs[n] = bf16( (x@W)[n] )                     (12.8 MB gather table)
//       out[d] = relu( dinv[d]*(xs[d]*dinv[d] + sum_e xs[src]*dinv[src]) + b )
// CSR by counting sort on dst. deg[d] = hist[d] + 1 (self-loop).
// 6 launches: init(zero+wfrag) -> convert_hist+gemm (fused, independent) ->
// scan1 -> scan3b -> esort -> aggr (software-pipelined gathers).
// ---------------------------------------------------------------------------

__device__ __forceinline__ unsigned int bf16pair(float a, float b) {
    unsigned int ua = __float_as_uint(a);
    ua = (ua + 0x7FFFu + ((ua >> 16) & 1u)) >> 16;   // RNE
    unsigned int ub = __float_as_uint(b);
    ub = (ub + 0x7FFFu + ((ub >> 16) & 1u)) >> 16;
    return ua | (ub << 16);
}
__device__ __forceinline__ float bflo(unsigned int u) { return __uint_as_float(u << 16); }
__device__ __forceinline__ float bfhi(unsigned int u) { return __uint_as_float(u & 0xFFFF0000u); }

// blocks 0..7: repack W into B-fragment-linear bf16; blocks 8..203: zero cnt.
__global__ void k_init(const float* __restrict__ W, unsigned int* __restrict__ Wf,
                       int* __restrict__ cnt) {
    int blk = blockIdx.x, t = threadIdx.x;
    if (blk < 8) {
        int id = blk * 256 + t;              // 0..2047
        int lane = id & 63;
        int ts = id >> 6;
        int t8 = ts >> 2, s = ts & 3;
        int col = t8 * 16 + (lane & 15);
        int k0 = s * 32 + (lane >> 4) * 8;
#pragma unroll
        for (int j = 0; j < 4; ++j) {
            float a = W[(k0 + 2 * j) * DD + col];
            float bb = W[(k0 + 2 * j + 1) * DD + col];
            Wf[id * 4 + j] = bf16pair(a, bb);
        }
    } else {
        int i = (blk - 8) * 256 + t;
        if (i < NN) cnt[i] = 0;
    }
}

// Fused: odd blocks convert+hist an edge chunk; even blocks run a GEMM tile.
// gemm: xs = bf16(x @ W) via mfma_f32_16x16x32_bf16, 4 waves, 16 rows/wave.
__global__ __launch_bounds__(256) void k_cvt_gemm(
    const int* __restrict__ ei, int* __restrict__ src, int* __restrict__ dst,
    int* __restrict__ cnt,
    const float* __restrict__ x, const unsigned int* __restrict__ Wf,
    unsigned short* __restrict__ xs, int n, int e) {
    const int blk = blockIdx.x, t = threadIdx.x;
    if (blk & 1) {  // ---- convert + histogram ----
        int i = (blk >> 1) * 256 + t;
        if (i >= e) return;
        bool is64 = (ei[1] == 0) & (ei[3] == 0) & (ei[5] == 0) & (ei[7] == 0);
        int s, d;
        if (is64) {
            s = ei[2 * i];
            d = ei[2 * (e + i)];
        } else {
            s = ei[i];
            d = ei[e + i];
        }
        src[i] = s;
        dst[i] = d;
        atomicAdd(&cnt[d], 1);
        return;
    }
    // ---- GEMM tile ----
    const int g = blk >> 1;
    if (g >= (n + 63) / 64) return;
    const int wave = t >> 6, lane = t & 63;
    const int row0 = g * 64 + wave * 16;
    const int arow = min(row0 + (lane & 15), n - 1);
    const int kbase = (lane >> 4) * 8;

    bf16x8 af[4];
#pragma unroll
    for (int s = 0; s < 4; ++s) {
        const float* px = &x[(size_t)arow * DD + s * 32 + kbase];
        float4 a0 = *(const float4*)px;
        float4 a1 = *(const float4*)(px + 4);
        unsigned int p[4];
        p[0] = bf16pair(a0.x, a0.y);
        p[1] = bf16pair(a0.z, a0.w);
        p[2] = bf16pair(a1.x, a1.y);
        p[3] = bf16pair(a1.z, a1.w);
        af[s] = __builtin_bit_cast(bf16x8, *(f32x4*)p);
    }
    f32x4 acc[8] = {};
#pragma unroll
    for (int s = 0; s < 4; ++s) {
#pragma unroll
        for (int t8 = 0; t8 < 8; ++t8) {
            bf16x8 bf = *(const bf16x8*)&Wf[((t8 * 4 + s) * 64 + lane) * 4];
            acc[t8] = __builtin_amdgcn_mfma_f32_16x16x32_bf16(af[s], bf, acc[t8], 0, 0, 0);
        }
    }
    const int rrow0 = row0 + (lane >> 4) * 4;
    const int colb = lane & 15;
#pragma unroll
    for (int i = 0; i < 4; ++i) {
        int r = rrow0 + i;
        if (r < n) {
#pragma unroll
            for (int t8 = 0; t8 < 8; ++t8) {
                float v = acc[t8][i];
                unsigned int uv = __float_as_uint(v);
                uv = (uv + 0x7FFFu + ((uv >> 16) & 1u)) >> 16;
                xs[(size_t)r * DD + t8 * 16 + colb] = (unsigned short)uv;
            }
        }
    }
}

// exclusive scan of cnt (1024/block) + dinv = rsqrt(cnt+1)
__global__ void k_scan1(const int* __restrict__ cnt, int* __restrict__ rowptr,
                        int* __restrict__ bsum, float* __restrict__ dinv, int n) {
    __shared__ int ts[256];
    int t = threadIdx.x;
    int base = blockIdx.x * 1024 + t * 4;
    int v[4];
    int s = 0;
#pragma unroll
    for (int i = 0; i < 4; ++i) {
        int idx = base + i;
        v[i] = (idx < n) ? cnt[idx] : 0;
        if (idx < n) dinv[idx] = rsqrtf((float)v[i] + 1.0f);
        s += v[i];
    }
    ts[t] = s;
    __syncthreads();
    for (int off = 1; off < 256; off <<= 1) {
        int x = (t >= off) ? ts[t - off] : 0;
        __syncthreads();
        ts[t] += x;
        __syncthreads();
    }
    if (t == 255) bsum[blockIdx.x] = ts[255];
    int run = ts[t] - s;
#pragma unroll
    for (int i = 0; i < 4; ++i) {
        int idx = base + i;
        if (idx < n) rowptr[idx] = run;
        run += v[i];
    }
}

// Finalize rowptr (+bsum prefix computed per-block) and init cursor.
__global__ void k_scan3b(int* __restrict__ rowptr, const int* __restrict__ bsum,
                         int* __restrict__ cursor, int n, int e) {
    __shared__ float sp;
    __shared__ int spi;
    int t = threadIdx.x;
    int c = blockIdx.x >> 2;  // 1024-chunk index for this block
    if (t == 0) {
        int acc = 0;
        for (int k = 0; k < c; ++k) acc += bsum[k];
        spi = acc;
    }
    __syncthreads();
    int pref = spi;
    int i = blockIdx.x * 256 + t;
    if (i < n) {
        int r = rowptr[i] + pref;
        rowptr[i] = r;
        cursor[i] = r;
    }
    if (i == n) rowptr[n] = e;
    (void)sp;
}

__global__ void k_esort(const int* __restrict__ src, const int* __restrict__ dst,
                        int* __restrict__ cursor, int* __restrict__ col, int e) {
    int i = blockIdx.x * blockDim.x + threadIdx.x;
    if (i >= e) return;
    int pos = atomicAdd(&cursor[dst[i]], 1);
    col[pos] = src[i];
}

// Wave per dst; lane owns 1 dword (2 bf16 dims). Software-pipelined masked
// batches of 8: gathers for batch i issue, next batch's col loads issue,
// then accumulate batch i (one gather round-trip per 8 edges, no serial tail).
__global__ __launch_bounds__(256) void k_aggr(
    const int* __restrict__ rowptr, const int* __restrict__ col,
    const unsigned int* __restrict__ xs, const float* __restrict__ dinv,
    const float* __restrict__ b, float* __restrict__ out) {
    int wid = (blockIdx.x * blockDim.x + threadIdx.x) >> 6;
    int lane = threadIdx.x & 63;
    if (wid >= NN) return;
    int beg = rowptr[wid], end = rowptr[wid + 1];
    float dvd = dinv[wid];
    unsigned int u = xs[(size_t)wid * 64 + lane];
    float ax = bflo(u) * dvd, ay = bfhi(u) * dvd;   // self-loop: xs[d]*dinv[d]

    int sA[8];
    int jb = beg;
    if (jb < end) {
#pragma unroll
        for (int k = 0; k < 8; ++k) sA[k] = col[min(jb + k, end - 1)];
    }
    while (jb < end) {
        float dv[8];
        unsigned int uu[8];
#pragma unroll
        for (int k = 0; k < 8; ++k) {
            dv[k] = dinv[sA[k]];
            uu[k] = xs[(size_t)sA[k] * 64 + lane];
        }
        int jn = jb + 8;
        int sN[8] = {0, 0, 0, 0, 0, 0, 0, 0};
        if (jn < end) {
#pragma unroll
            for (int k = 0; k < 8; ++k) sN[k] = col[min(jn + k, end - 1)];
        }
#pragma unroll
        for (int k = 0; k < 8; ++k) {
            float m = (jb + k < end) ? dv[k] : 0.0f;
            ax = fmaf(bflo(uu[k]), m, ax);
            ay = fmaf(bfhi(uu[k]), m, ay);
        }
#pragma unroll
        for (int k = 0; k < 8; ++k) sA[k] = sN[k];
        jb = jn;
    }
    float2 bb = *(const float2*)&b[lane * 2];
    float ox = fmaxf(fmaf(ax, dvd, bb.x), 0.f);
    float oy = fmaxf(fmaf(ay, dvd, bb.y), 0.f);
    *(float2*)&out[(size_t)wid * DD + lane * 2] = make_float2(ox, oy);
}

extern "C" void kernel_launch(void* const* d_in, const int* in_sizes, int n_in,
                              void* d_out, int out_size, void* d_ws, size_t ws_size,
                              hipStream_t stream) {
    const float* x  = (const float*)d_in[0];
    const int*   ei = (const int*)d_in[1];
    const float* W  = (const float*)d_in[2];
    const float* b  = (const float*)d_in[3];
    float* out = (float*)d_out;

    char* p = (char*)d_ws;
    float*          dinv   = (float*)p;          p += NN * sizeof(float);
    unsigned short* xs     = (unsigned short*)p; p += (size_t)NN * DD * sizeof(unsigned short);
    int*            srcW   = (int*)p;            p += NE * sizeof(int);
    int*            dstW   = (int*)p;            p += NE * sizeof(int);
    int*            colW   = (int*)p;            p += NE * sizeof(int);
    int*            cnt    = (int*)p;            p += NN * sizeof(int);
    int*            rowptr = (int*)p;            p += (NN + 1) * sizeof(int);
    int*            cursor = (int*)p;            p += NN * sizeof(int);
    int*            bsum   = (int*)p;            p += 64 * sizeof(int);
    unsigned int*   Wf     = (unsigned int*)p;   p += 2048 * 4 * sizeof(unsigned int);

    const int nb_e  = (NE + 255) / 256;          // 1954
    const int nscan = (NN + 1023) / 1024;        // 49

    k_init<<<8 + (NN + 255) / 256, 256, 0, stream>>>(W, Wf, cnt);
    k_cvt_gemm<<<2 * nb_e, 256, 0, stream>>>(ei, srcW, dstW, cnt, x, Wf, xs, NN, NE);
    k_scan1<<<nscan, 256, 0, stream>>>(cnt, rowptr, bsum, dinv, NN);
    k_scan3b<<<(NN + 256) / 256, 256, 0, stream>>>(rowptr, bsum, cursor, NN, NE);
    k_esort<<<nb_e, 256, 0, stream>>>(srcW, dstW, cursor, colW, NE);
    k_aggr<<<(NN * 64 + 255) / 256, 256, 0, stream>>>(rowptr, colW,
                                                      (const unsigned int*)xs, dinv, b, out);
}